// Round 9
// baseline (115.658 us; speedup 1.0000x reference)
//
#include <hip/hip_runtime.h>
#include <hip/hip_bf16.h>
#include <cstdint>
#include <cstddef>

#define NN 10000
#define NE 160000
#define DD 300
#define KP 320      // K padded to 10 MFMA steps of 32
#define NPAD 320    // W rows padded to 20 tiles of 16
#define MTILES 625  // NN/16
#define CAP 64      // bucket capacity per node (max degree ~35 for this graph)
#define HCOL 160    // column half (bf16) -> 320 B, 20 uint4
#define HU4 20      // uint4 per half-row

using bf16x8 = __attribute__((ext_vector_type(8))) __bf16;
using f32x4  = __attribute__((ext_vector_type(4))) float;

// ---------------- K1: zero cnt + convert W1,W2 -> bf16 [NPAD][KP] ----------------

__global__ __launch_bounds__(256) void zero_convw_kernel(const float* __restrict__ W1,
                                                         const float* __restrict__ W2,
                                                         __bf16* __restrict__ W1b,
                                                         __bf16* __restrict__ W2b,
                                                         int* __restrict__ cnt) {
    const int t = blockIdx.x * 256 + threadIdx.x;   // 0..12799
    if (t < NN) cnt[t] = 0;
    const int n = t / (KP / 8);          // 0..319
    const int k0 = (t % (KP / 8)) * 8;   // 0..312
    bf16x8 v1, v2;
#pragma unroll
    for (int i = 0; i < 8; ++i) {
        const int k = k0 + i;
        const bool in = (n < DD) && (k < DD);
        v1[i] = (__bf16)(in ? W1[n * DD + k] : 0.f);
        v2[i] = (__bf16)(in ? W2[n * DD + k] : 0.f);
    }
    *(bf16x8*)(W1b + (size_t)n * KP + k0) = v1;
    *(bf16x8*)(W2b + (size_t)n * KP + k0) = v2;
}

// ---------------- K2: bucket fill ----------------

__global__ void bucket_kernel(const int* __restrict__ src, const int* __restrict__ dst,
                              int* __restrict__ cnt, int* __restrict__ bucket) {
    int e = blockIdx.x * 256 + threadIdx.x;
    if (e < NE) {
        int d = dst[e];
        int pos = atomicAdd(&cnt[d], 1);
        if (pos < CAP) bucket[d * CAP + pos] = src[e];
    }
}

// ---------------- GEMM: G[m][n] = sum_k A[m][k]*W[n][k]  (bf16 out, no bias) ----------------

template <bool F32IN>
__global__ __launch_bounds__(256, 1) void gemm_kernel(const void* __restrict__ Ap,
                                                      const __bf16* __restrict__ Wb,
                                                      __bf16* __restrict__ G) {
    const int w = threadIdx.x >> 6;
    const int lane = threadIdx.x & 63;
    const int r = lane & 15;    // A row-in-tile / B col / D col
    const int q = lane >> 4;    // k-block select / D row-block

    bf16x8 b[5][10];
    const __bf16* Bb = Wb + (size_t)r * KP + q * 8;
#pragma unroll
    for (int t = 0; t < 5; ++t) {
        const __bf16* Bt = Bb + (size_t)(w * 5 + t) * 16 * KP;
#pragma unroll
        for (int ks = 0; ks < 10; ++ks)
            b[t][ks] = *(const bf16x8*)(Bt + ks * 32);
    }

    for (int mt = blockIdx.x; mt < MTILES; mt += gridDim.x) {
        f32x4 acc[5] = {};
        if constexpr (F32IN) {
            const float* Ab = (const float*)Ap + (size_t)(mt * 16 + r) * DD + q * 8;
#pragma unroll
            for (int ks = 0; ks < 9; ++ks) {
                f32x4 lo = *(const f32x4*)(Ab + ks * 32);
                f32x4 hi = *(const f32x4*)(Ab + ks * 32 + 4);
                bf16x8 af;
#pragma unroll
                for (int j = 0; j < 4; ++j) { af[j] = (__bf16)lo[j]; af[4 + j] = (__bf16)hi[j]; }
#pragma unroll
                for (int t = 0; t < 5; ++t)
                    acc[t] = __builtin_amdgcn_mfma_f32_16x16x32_bf16(af, b[t][ks], acc[t], 0, 0, 0);
            }
            {   // ks = 9: k = 288 + q*8 + j, guard k < 300
                bf16x8 af;
#pragma unroll
                for (int j = 0; j < 8; ++j) {
                    int k = 288 + q * 8 + j;
                    af[j] = (__bf16)((k < DD) ? Ab[288 + j] : 0.f);
                }
#pragma unroll
                for (int t = 0; t < 5; ++t)
                    acc[t] = __builtin_amdgcn_mfma_f32_16x16x32_bf16(af, b[t][9], acc[t], 0, 0, 0);
            }
        } else {
            const __bf16* Ab = (const __bf16*)Ap + (size_t)(mt * 16 + r) * KP + q * 8;
#pragma unroll
            for (int ks = 0; ks < 10; ++ks) {
                bf16x8 af = *(const bf16x8*)(Ab + ks * 32);
#pragma unroll
                for (int t = 0; t < 5; ++t)
                    acc[t] = __builtin_amdgcn_mfma_f32_16x16x32_bf16(af, b[t][ks], acc[t], 0, 0, 0);
            }
        }
#pragma unroll
        for (int t = 0; t < 5; ++t) {
            const int n = (w * 5 + t) * 16 + r;
#pragma unroll
            for (int j = 0; j < 4; ++j) {
                const int m = mt * 16 + q * 4 + j;
                G[(size_t)m * KP + n] = (__bf16)acc[t][j];
            }
        }
    }
}

// ---------------- aggregation, column-half split, 2 neighbors/wave ----------------
// Grid = 2*NN blocks: half = blockIdx.x / NN (all half-0 blocks dispatch first, so each
// phase's gather working set = 3.2 MB half-G, L2-resident per XCD). Block = 4 waves, one
// node. Within a wave: lanes 0-19 gather neighbor 2jj, lanes 32-51 gather 2jj+1 (per-lane
// shfl index); halves merged via shfl_down(32), then cross-wave via LDS.
// LAST: f32 [NN][DD] out; else bf16 [NN][KP] out with zero pads.

template <bool LAST>
__global__ __launch_bounds__(256) void agg_kernel(const __bf16* __restrict__ G,
                                                  const float* __restrict__ bias,
                                                  void* __restrict__ outp,
                                                  const int* __restrict__ cnt,
                                                  const int* __restrict__ bucket) {
    __shared__ float part[3][HCOL];
    const int wv = threadIdx.x >> 6;       // 0..3
    const int lane = threadIdx.x & 63;
    const int sub = lane & 31;             // 0..31
    const int hi = lane >> 5;              // neighbor slot 0/1
    const int half = blockIdx.x / NN;      // column half
    const int node = blockIdx.x - half * NN;
    const bool act = sub < HU4;            // 20 uint4 = 320 B half-row
    const uint4* hv = (const uint4*)G + half * HU4;   // row stride KP/8 = 40 uint4

    const int c = min(cnt[node], CAP);
    const int q0 = (c * wv) >> 2;
    const int q1 = (c * (wv + 1)) >> 2;
    const int myCnt = q1 - q0;

    float acc[8] = {};
    auto addv = [&](uint4 v) {
        uint32_t u[4] = {v.x, v.y, v.z, v.w};
#pragma unroll
        for (int i = 0; i < 4; ++i) {
            acc[2 * i]     += __uint_as_float(u[i] << 16);
            acc[2 * i + 1] += __uint_as_float(u[i] & 0xffff0000u);
        }
    };

    if (wv == 0 && hi == 0 && act) addv(hv[(size_t)node * (KP / 8) + sub]);   // self-loop

    int idx = 0;
    if (lane < myCnt) idx = bucket[node * CAP + q0 + lane];
    const int rounds = (myCnt + 1) >> 1;
    int jj = 0;
    for (; jj + 2 <= rounds; jj += 2) {    // 2 rounds unrolled: up to 4 neighbors in flight
        const int i0 = 2 * jj + hi, i1 = i0 + 2;
        const int n0 = __shfl(idx, i0), n1 = __shfl(idx, i1);
        const bool b0 = act && (i0 < myCnt), b1 = act && (i1 < myCnt);
        uint4 v0, v1;
        if (b0) v0 = hv[(size_t)n0 * (KP / 8) + sub];
        if (b1) v1 = hv[(size_t)n1 * (KP / 8) + sub];
        if (b0) addv(v0);
        if (b1) addv(v1);
    }
    if (jj < rounds) {
        const int i0 = 2 * jj + hi;
        const int nb = __shfl(idx, i0);
        if (act && i0 < myCnt) addv(hv[(size_t)nb * (KP / 8) + sub]);
    }

    // merge neighbor-slot halves: lane s += lane s+32
#pragma unroll
    for (int i = 0; i < 8; ++i) acc[i] += __shfl_down(acc[i], 32);

    // cross-wave combine via LDS (lanes 0..19 of each wave hold the wave partial)
    if (wv > 0 && hi == 0 && act) {
        *(f32x4*)&part[wv - 1][sub * 8]     = (f32x4){acc[0], acc[1], acc[2], acc[3]};
        *(f32x4*)&part[wv - 1][sub * 8 + 4] = (f32x4){acc[4], acc[5], acc[6], acc[7]};
    }
    __syncthreads();
    if (wv > 0 || hi != 0 || !act) return;

#pragma unroll
    for (int p = 0; p < 3; ++p) {
        f32x4 p0 = *(const f32x4*)&part[p][sub * 8];
        f32x4 p1 = *(const f32x4*)&part[p][sub * 8 + 4];
#pragma unroll
        for (int i = 0; i < 4; ++i) { acc[i] += p0[i]; acc[4 + i] += p1[i]; }
    }

    const int c0 = half * HCOL + sub * 8;
    if (LAST) {
        float* out = (float*)outp + (size_t)node * DD;
#pragma unroll
        for (int i = 0; i < 8; ++i) {
            int n = c0 + i;
            if (n < DD) {
                float v = acc[i] + bias[n];
                out[n] = v > 0.f ? v : 0.f;
            }
        }
    } else {
        bf16x8 o;
#pragma unroll
        for (int i = 0; i < 8; ++i) {
            int n = c0 + i;
            float v = (n < DD) ? acc[i] + bias[n] : 0.f;
            v = v > 0.f ? v : 0.f;
            o[i] = (__bf16)v;
        }
        *(bf16x8*)((__bf16*)outp + (size_t)node * KP + c0) = o;
    }
}

// ---------------- launch ----------------

extern "C" void kernel_launch(void* const* d_in, const int* in_sizes, int n_in,
                              void* d_out, int out_size, void* d_ws, size_t ws_size,
                              hipStream_t stream) {
    const float* features = (const float*)d_in[0];
    const int*   src      = (const int*)d_in[1];
    const int*   dst      = (const int*)d_in[2];
    const float* W1       = (const float*)d_in[3];
    const float* b1       = (const float*)d_in[4];
    const float* W2       = (const float*)d_in[5];
    const float* b2       = (const float*)d_in[6];
    float* out = (float*)d_out;

    char* ws = (char*)d_ws;
    size_t off = 0;
    auto alloc = [&](size_t bytes) -> void* {
        void* p = ws + off;
        off += (bytes + 255) & ~(size_t)255;
        return p;
    };
    int*    cnt    = (int*)alloc(NN * sizeof(int));
    int*    bucket = (int*)alloc((size_t)NN * CAP * sizeof(int));
    __bf16* W1b    = (__bf16*)alloc((size_t)NPAD * KP * sizeof(__bf16));
    __bf16* W2b    = (__bf16*)alloc((size_t)NPAD * KP * sizeof(__bf16));
    __bf16* Gbuf   = (__bf16*)alloc((size_t)NN * KP * sizeof(__bf16));
    __bf16* h1b    = (__bf16*)alloc((size_t)NN * KP * sizeof(__bf16));
    (void)ws_size; (void)in_sizes; (void)n_in; (void)out_size;

    // K1: zero cnt + convert W
    hipLaunchKernelGGL(zero_convw_kernel, dim3(50), dim3(256), 0, stream, W1, W2, W1b, W2b, cnt);
    // K2: bucket fill
    hipLaunchKernelGGL(bucket_kernel, dim3((NE + 255) / 256), dim3(256), 0, stream, src, dst, cnt, bucket);

    // layer 1: G1 = features . W1^T ; h1 = relu(agg(G1) + b1)
    hipLaunchKernelGGL((gemm_kernel<true>), dim3(256), dim3(256), 0, stream,
                       (const void*)features, W1b, Gbuf);
    hipLaunchKernelGGL((agg_kernel<false>), dim3(2 * NN), dim3(256), 0, stream,
                       Gbuf, b1, (void*)h1b, cnt, bucket);
    // layer 2: G2 = h1 . W2^T ; out = relu(agg(G2) + b2)
    hipLaunchKernelGGL((gemm_kernel<false>), dim3(256), dim3(256), 0, stream,
                       (const void*)h1b, W2b, Gbuf);
    hipLaunchKernelGGL((agg_kernel<true>), dim3(2 * NN), dim3(256), 0, stream,
                       Gbuf, b2, (void*)out, cnt, bucket);
}

// Round 10
// 98.685 us; speedup vs baseline: 1.1720x; 1.1720x over previous
//
#include <hip/hip_runtime.h>
#include <hip/hip_bf16.h>
#include <cstdint>
#include <cstddef>

#define NN 10000
#define NE 160000
#define DD 300
#define KP 320      // K padded to 10 MFMA steps of 32
#define NPAD 320    // W rows padded to 20 tiles of 16
#define MTILES 625  // NN/16
#define NRANGE 4    // source-ID ranges (L2 phasing): 2500 rows x 640 B = 1.6 MB slice
#define RSPAN 2500  // NN / NRANGE
#define RCAP 32     // bucket slots per node per range (mean degree/range = 4)

using bf16x8 = __attribute__((ext_vector_type(8))) __bf16;
using f32x4  = __attribute__((ext_vector_type(4))) float;

// ---------------- K1: zero cnt[NN][4] + convert W1,W2 -> bf16 [NPAD][KP] ----------------
// grid 50 x 256 = 12800 threads; thread t converts 8 cols of one W row (12800*8 = 102400
// = NPAD*KP exactly); threads t<NN zero the per-node int4 range-counters.

__global__ __launch_bounds__(256) void zero_convw_kernel(const float* __restrict__ W1,
                                                         const float* __restrict__ W2,
                                                         __bf16* __restrict__ W1b,
                                                         __bf16* __restrict__ W2b,
                                                         int* __restrict__ cnt) {
    const int t = blockIdx.x * 256 + threadIdx.x;   // 0..12799
    if (t < NN) ((int4*)cnt)[t] = (int4){0, 0, 0, 0};
    const int n = t / (KP / 8);          // 0..319
    const int k0 = (t % (KP / 8)) * 8;   // 0..312
    bf16x8 v1, v2;
#pragma unroll
    for (int i = 0; i < 8; ++i) {
        const int k = k0 + i;
        const bool in = (n < DD) && (k < DD);
        v1[i] = (__bf16)(in ? W1[n * DD + k] : 0.f);
        v2[i] = (__bf16)(in ? W2[n * DD + k] : 0.f);
    }
    *(bf16x8*)(W1b + (size_t)n * KP + k0) = v1;
    *(bf16x8*)(W2b + (size_t)n * KP + k0) = v2;
}

// ---------------- K2: bucket fill, partitioned by source range ----------------

__global__ void bucket_kernel(const int* __restrict__ src, const int* __restrict__ dst,
                              int* __restrict__ cnt, int* __restrict__ bucket) {
    int e = blockIdx.x * 256 + threadIdx.x;
    if (e < NE) {
        int d = dst[e];
        int s = src[e];
        int r = s / RSPAN;                       // 0..3
        int pos = atomicAdd(&cnt[d * NRANGE + r], 1);
        if (pos < RCAP) bucket[d * (NRANGE * RCAP) + r * RCAP + pos] = s;
    }
}

// ---------------- GEMM: G[m][n] = sum_k A[m][k]*W[n][k]  (bf16 out, no bias) ----------------

template <bool F32IN>
__global__ __launch_bounds__(256, 1) void gemm_kernel(const void* __restrict__ Ap,
                                                      const __bf16* __restrict__ Wb,
                                                      __bf16* __restrict__ G) {
    const int w = threadIdx.x >> 6;
    const int lane = threadIdx.x & 63;
    const int r = lane & 15;    // A row-in-tile / B col / D col
    const int q = lane >> 4;    // k-block select / D row-block

    bf16x8 b[5][10];
    const __bf16* Bb = Wb + (size_t)r * KP + q * 8;
#pragma unroll
    for (int t = 0; t < 5; ++t) {
        const __bf16* Bt = Bb + (size_t)(w * 5 + t) * 16 * KP;
#pragma unroll
        for (int ks = 0; ks < 10; ++ks)
            b[t][ks] = *(const bf16x8*)(Bt + ks * 32);
    }

    for (int mt = blockIdx.x; mt < MTILES; mt += gridDim.x) {
        f32x4 acc[5] = {};
        if constexpr (F32IN) {
            const float* Ab = (const float*)Ap + (size_t)(mt * 16 + r) * DD + q * 8;
#pragma unroll
            for (int ks = 0; ks < 9; ++ks) {
                f32x4 lo = *(const f32x4*)(Ab + ks * 32);
                f32x4 hi = *(const f32x4*)(Ab + ks * 32 + 4);
                bf16x8 af;
#pragma unroll
                for (int j = 0; j < 4; ++j) { af[j] = (__bf16)lo[j]; af[4 + j] = (__bf16)hi[j]; }
#pragma unroll
                for (int t = 0; t < 5; ++t)
                    acc[t] = __builtin_amdgcn_mfma_f32_16x16x32_bf16(af, b[t][ks], acc[t], 0, 0, 0);
            }
            {   // ks = 9: k = 288 + q*8 + j, guard k < 300
                bf16x8 af;
#pragma unroll
                for (int j = 0; j < 8; ++j) {
                    int k = 288 + q * 8 + j;
                    af[j] = (__bf16)((k < DD) ? Ab[288 + j] : 0.f);
                }
#pragma unroll
                for (int t = 0; t < 5; ++t)
                    acc[t] = __builtin_amdgcn_mfma_f32_16x16x32_bf16(af, b[t][9], acc[t], 0, 0, 0);
            }
        } else {
            const __bf16* Ab = (const __bf16*)Ap + (size_t)(mt * 16 + r) * KP + q * 8;
#pragma unroll
            for (int ks = 0; ks < 10; ++ks) {
                bf16x8 af = *(const bf16x8*)(Ab + ks * 32);
#pragma unroll
                for (int t = 0; t < 5; ++t)
                    acc[t] = __builtin_amdgcn_mfma_f32_16x16x32_bf16(af, b[t][ks], acc[t], 0, 0, 0);
            }
        }
#pragma unroll
        for (int t = 0; t < 5; ++t) {
            const int n = (w * 5 + t) * 16 + r;
#pragma unroll
            for (int j = 0; j < 4; ++j) {
                const int m = mt * 16 + q * 4 + j;
                G[(size_t)m * KP + n] = (__bf16)acc[t][j];
            }
        }
    }
}

// ---------------- aggregation over G + bias + relu; 2 waves per node, range-phased ----------------
// out[n] = relu(G[n] + sum_{e:dst=n} G[src[e]] + b)
// Block = 256 = 2 nodes x 2 waves (R7 structure). Neighbor lists are partitioned by
// source range (4 x 1.6 MB G-slices); all blocks process range 0..3 in order, so the
// device-wide gather working set at any instant ~ one slice -> L2-resident per XCD.
// Wave half h takes sub-list [cr*h/2, cr*(h+1)/2) of each range; partials via LDS.
// LAST: f32 [NN][DD] out; else bf16 [NN][KP] out with zero pads.

template <bool LAST>
__global__ __launch_bounds__(256) void agg_kernel(const __bf16* __restrict__ G,
                                                  const float* __restrict__ bias,
                                                  void* __restrict__ outp,
                                                  const int* __restrict__ cnt,
                                                  const int* __restrict__ bucket) {
    __shared__ float part[2][KP];
    const int w = threadIdx.x >> 6;        // 0..3
    const int lane = threadIdx.x & 63;
    const int nsub = w >> 1;               // node slot in block
    const int half = w & 1;                // list half
    const int node = blockIdx.x * 2 + nsub;   // grid 5000 x 2 = 10000 exactly
    const bool act = lane < (KP / 8);      // 40 lanes x 8 bf16 = 320 cols
    const uint4* hv = (const uint4*)G;     // row stride KP/8 = 40

    float acc[8] = {};
    auto addv = [&](uint4 v) {
        uint32_t u[4] = {v.x, v.y, v.z, v.w};
#pragma unroll
        for (int i = 0; i < 4; ++i) {
            acc[2 * i]     += __uint_as_float(u[i] << 16);
            acc[2 * i + 1] += __uint_as_float(u[i] & 0xffff0000u);
        }
    };

    if (!half && act) addv(hv[(size_t)node * (KP / 8) + lane]);   // self-loop

    // per-range counts + index lists (all loads independent, issued up front)
    const int4 c4 = ((const int4*)cnt)[node];
    int crs[NRANGE] = {min(c4.x, RCAP), min(c4.y, RCAP), min(c4.z, RCAP), min(c4.w, RCAP)};
    int idxr[NRANGE], mc[NRANGE];
#pragma unroll
    for (int r = 0; r < NRANGE; ++r) {
        const int h0 = crs[r] >> 1;
        mc[r] = half ? (crs[r] - h0) : h0;
        const int base = node * (NRANGE * RCAP) + r * RCAP + (half ? h0 : 0);
        idxr[r] = (lane < mc[r]) ? bucket[base + lane] : 0;
    }

    // gather, range 0 -> 3 (device-wide phase coherence)
#pragma unroll
    for (int r = 0; r < NRANGE; ++r) {
        const int myCnt = mc[r];
        int j = 0;
        for (; j + 2 <= myCnt; j += 2) {
            const int n0 = __shfl(idxr[r], j), n1 = __shfl(idxr[r], j + 1);
            if (act) {
                uint4 v0 = hv[(size_t)n0 * (KP / 8) + lane];
                uint4 v1 = hv[(size_t)n1 * (KP / 8) + lane];
                addv(v0); addv(v1);
            }
        }
        if (j < myCnt) {
            const int nb = __shfl(idxr[r], j);
            if (act) addv(hv[(size_t)nb * (KP / 8) + lane]);
        }
    }

    // combine wave pair through LDS
    if (half && act) {
        *(f32x4*)&part[nsub][lane * 8]     = (f32x4){acc[0], acc[1], acc[2], acc[3]};
        *(f32x4*)&part[nsub][lane * 8 + 4] = (f32x4){acc[4], acc[5], acc[6], acc[7]};
    }
    __syncthreads();
    if (half || !act) return;

    f32x4 p0 = *(const f32x4*)&part[nsub][lane * 8];
    f32x4 p1 = *(const f32x4*)&part[nsub][lane * 8 + 4];
#pragma unroll
    for (int i = 0; i < 4; ++i) { acc[i] += p0[i]; acc[4 + i] += p1[i]; }

    const int c0 = lane * 8;
    if (LAST) {
        float* out = (float*)outp + (size_t)node * DD + c0;
#pragma unroll
        for (int i = 0; i < 8; ++i) {
            int n = c0 + i;
            if (n < DD) {
                float v = acc[i] + bias[n];
                out[i] = v > 0.f ? v : 0.f;
            }
        }
    } else {
        bf16x8 o;
#pragma unroll
        for (int i = 0; i < 8; ++i) {
            int n = c0 + i;
            float v = (n < DD) ? acc[i] + bias[n] : 0.f;
            v = v > 0.f ? v : 0.f;
            o[i] = (__bf16)v;
        }
        *(bf16x8*)((__bf16*)outp + (size_t)node * KP + c0) = o;
    }
}

// ---------------- launch ----------------

extern "C" void kernel_launch(void* const* d_in, const int* in_sizes, int n_in,
                              void* d_out, int out_size, void* d_ws, size_t ws_size,
                              hipStream_t stream) {
    const float* features = (const float*)d_in[0];
    const int*   src      = (const int*)d_in[1];
    const int*   dst      = (const int*)d_in[2];
    const float* W1       = (const float*)d_in[3];
    const float* b1       = (const float*)d_in[4];
    const float* W2       = (const float*)d_in[5];
    const float* b2       = (const float*)d_in[6];
    float* out = (float*)d_out;

    char* ws = (char*)d_ws;
    size_t off = 0;
    auto alloc = [&](size_t bytes) -> void* {
        void* p = ws + off;
        off += (bytes + 255) & ~(size_t)255;
        return p;
    };
    int*    cnt    = (int*)alloc((size_t)NN * NRANGE * sizeof(int));
    int*    bucket = (int*)alloc((size_t)NN * NRANGE * RCAP * sizeof(int));
    __bf16* W1b    = (__bf16*)alloc((size_t)NPAD * KP * sizeof(__bf16));
    __bf16* W2b    = (__bf16*)alloc((size_t)NPAD * KP * sizeof(__bf16));
    __bf16* Gbuf   = (__bf16*)alloc((size_t)NN * KP * sizeof(__bf16));
    __bf16* h1b    = (__bf16*)alloc((size_t)NN * KP * sizeof(__bf16));
    (void)ws_size; (void)in_sizes; (void)n_in; (void)out_size;

    // K1: zero cnt + convert W
    hipLaunchKernelGGL(zero_convw_kernel, dim3(50), dim3(256), 0, stream, W1, W2, W1b, W2b, cnt);
    // K2: bucket fill (range-partitioned)
    hipLaunchKernelGGL(bucket_kernel, dim3((NE + 255) / 256), dim3(256), 0, stream, src, dst, cnt, bucket);

    // layer 1: G1 = features . W1^T ; h1 = relu(agg(G1) + b1)
    hipLaunchKernelGGL((gemm_kernel<true>), dim3(256), dim3(256), 0, stream,
                       (const void*)features, W1b, Gbuf);
    hipLaunchKernelGGL((agg_kernel<false>), dim3(NN / 2), dim3(256), 0, stream,
                       Gbuf, b1, (void*)h1b, cnt, bucket);
    // layer 2: G2 = h1 . W2^T ; out = relu(agg(G2) + b2)
    hipLaunchKernelGGL((gemm_kernel<false>), dim3(256), dim3(256), 0, stream,
                       (const void*)h1b, W2b, Gbuf);
    hipLaunchKernelGGL((agg_kernel<true>), dim3(NN / 2), dim3(256), 0, stream,
                       Gbuf, b2, (void*)out, cnt, bucket);
}